// Round 13
// baseline (60.895 us; speedup 1.0000x reference)
//
#include <hip/hip_runtime.h>

// KNNInteractionGraph — R12 row engine, TWO rows per wave (4096 waves).
// N=8192, K=32, CUTOFF=10, batch sorted (molecules contiguous, n ~ 64+-8).
//
// R13 experiment: all-rounds evidence fits ~1.3ns per-WAVE dispatch/placement
// cost (R9: +11.5us per 8192-wave dispatch; R7: per-WG repack neutral; R8/R11/
// R12: compute cuts yield only ~1us each). R10's contrary datum is confounded
// by register spills. Test cleanly: same per-row body (noinline, tiny regs,
// bitwise-identical outputs), 2 sequential rows per wave -> half the waves.
//
// Output (float32, 3*N*K): [indices | centers | weights].

#define CUTOFF_F 10.0f
#define ROWS_PER_WAVE 2
#define WAVES_PER_BLOCK 4
#define ROWS_PER_BLOCK (ROWS_PER_WAVE * WAVES_PER_BLOCK)   // 8
#define KEY_TRUNC 0xFFFFFF80u     // keep 25 high bits of v, low 7 bits = col

__device__ __forceinline__ float readlane_f(float v, int lane) {
    return __int_as_float(__builtin_amdgcn_readlane(__float_as_int(v), lane));
}
__device__ __forceinline__ int readlane_i(int v, int lane) {
    return __builtin_amdgcn_readlane(v, lane);
}
__device__ __forceinline__ float bperm_f(float v, int srclane) {
    return __int_as_float(__builtin_amdgcn_ds_bpermute(srclane << 2, __float_as_int(v)));
}

// DPP xor-permutations: quad_perm xor1 = 0xB1, quad_perm xor2 = 0x4E,
// row_ror:8 = 0x128 (== xor8 within 16-lane rows). All lanes active (EXEC=~0).
template <int CTRL>
__device__ __forceinline__ unsigned dpp_u32(unsigned x) {
    return (unsigned)__builtin_amdgcn_update_dpp((int)x, (int)x, CTRL, 0xf, 0xf, true);
}
__device__ __forceinline__ unsigned stage_shfl32(unsigned x, int j) {
    if (j == 1) return dpp_u32<0xB1>(x);
    if (j == 2) return dpp_u32<0x4E>(x);
    if (j == 8) return dpp_u32<0x128>(x);
    return (unsigned)__shfl_xor((int)x, j, 64);
}

// Reference-exact masked distance (gram expansion, f32, no FMA contraction):
__device__ __forceinline__ float dist_v(float4 pr, float4 pc, bool diag) {
    if (diag) return CUTOFF_F;
    float dot = __fadd_rn(__fadd_rn(__fmul_rn(pr.x, pc.x), __fmul_rn(pr.y, pc.y)),
                          __fmul_rn(pr.z, pc.z));
    float sq = __fsub_rn(__fadd_rn(pr.w, pc.w), __fadd_rn(dot, dot));
    sq = fmaxf(sq, 0.0f);
    float d = (sq > 0.0f) ? __fsqrt_rn(sq) : 0.0f;
    return (d > CUTOFF_F) ? CUTOFF_F : d;
}

__device__ __forceinline__ float4 load_pos4(const float* __restrict__ pos, int g) {
    float x = pos[g * 3 + 0];
    float y = pos[g * 3 + 1];
    float z = pos[g * 3 + 2];
    float sq = __fadd_rn(__fadd_rn(__fmul_rn(x, x), __fmul_rn(y, y)), __fmul_rn(z, z));
    return make_float4(x, y, z, sq);
}

// Ascending bitonic sort of 64 u32 keys, one per lane.
__device__ __forceinline__ unsigned bitonic64_u32(unsigned key, int lane) {
#pragma unroll
    for (int k = 2; k <= 64; k <<= 1) {
#pragma unroll
        for (int j = k >> 1; j > 0; j >>= 1) {
            const unsigned pk = stage_shfl32(key, j);
            const bool take_min = (((lane & j) == 0) == ((lane & k) == 0));
            key = ((pk < key) == take_min) ? pk : key;
        }
    }
    return key;
}

// Ascending bitonic sort of 128 u32 keys, two per lane (A: vpos=lane, B: 64+lane).
__device__ __forceinline__ void bitonic128_u32(unsigned& ka, unsigned& kb, int lane) {
#pragma unroll
    for (int k = 2; k <= 128; k <<= 1) {
#pragma unroll
        for (int j = k >> 1; j > 0; j >>= 1) {
            if (j == 64) {            // final k=128 merge: in-lane A<->B
                const unsigned mn = min(ka, kb);
                const unsigned mx = max(ka, kb);
                ka = mn; kb = mx;
            } else {
                const unsigned pa = stage_shfl32(ka, j);
                const unsigned pb = stage_shfl32(kb, j);
                const bool low = ((lane & j) == 0);
                const bool upA = ((lane & k) == 0);
                const bool upB = (k == 64) ? false : upA;
                ka = ((pa < ka) == (low == upA)) ? pa : ka;
                kb = ((pb < kb) == (low == upB)) ? pb : kb;
            }
        }
    }
}

// Cold fill: slots [m,K) get CUTOFF at globally-smallest masked indices:
// {0..start-1} U {in-mol masked (v==CUTOFF)} U {end..N-1} (lax.top_k tie order).
template <int NCH>
__device__ __forceinline__ void do_fill(const float* v, int m, int K, int lane,
                                        int start, int end, int n, int r, int NK,
                                        float* __restrict__ out) {
    const int mm = n - m;
    for (int fb = 0; fb < K - m; fb += 64) {
        const int t = fb + lane;
        const bool active = t < (K - m);
        int idx = 0;
        bool found = false;
        if (active) {
            if (t < start)            { idx = t;                      found = true; }
            else if (t - start >= mm) { idx = end + (t - start - mm); found = true; }
        }
        if (__any(active && !found)) {
            int cnt = 0;
#pragma unroll
            for (int jj = 0; jj < NCH; ++jj) {
                const int base = 64 * jj;
                const int lim  = min(n - base, 64);
                for (int cc = 0; cc < lim; ++cc) {
                    if (readlane_f(v[jj], cc) == CUTOFF_F) {
                        if (active && !found && cnt == t - start) {
                            idx = start + base + cc; found = true;
                        }
                        ++cnt;
                    }
                }
            }
        }
        if (active) {
            const int o = r * K + m + t;
            out[o]          = (float)idx;
            out[2 * NK + o] = CUTOFF_F;
        }
    }
}

// ---------------- hot cores ---------------------------------------------------
__device__ __forceinline__ void row_core_sort64(const float* __restrict__ pos,
                                                int n, int lane,
                                                int start, int end, int r,
                                                float* __restrict__ out,
                                                int NK, int K) {
    const int c = lane;
    const int d = r - start;                       // uniform, in [0, n)
    const int g = start + min(c, n - 1);           // clamped column load
    const float x = pos[g * 3 + 0];
    const float y = pos[g * 3 + 1];
    const float z = pos[g * 3 + 2];
    const float sq = __fadd_rn(__fadd_rn(__fmul_rn(x, x), __fmul_rn(y, y)),
                               __fmul_rn(z, z));
    const float4 pc = make_float4(x, y, z, sq);
    const float4 pr = make_float4(readlane_f(x, d), readlane_f(y, d),
                                  readlane_f(z, d), readlane_f(sq, d));
    float v[1];
    v[0] = (c < n && c != d) ? dist_v(pr, pc, false) : CUTOFF_F;

    unsigned key = (((unsigned)__float_as_int(v[0])) & KEY_TRUNC) | (unsigned)c;
    key = bitonic64_u32(key, lane);

    const int   cs = (int)(key & 0x7Fu);
    const float vx = bperm_f(v[0], cs);            // exact weight by sorted col
    if (lane < K && vx < CUTOFF_F) {               // sorted slot = lane (coalesced)
        const int o = r * K + lane;
        out[o]          = (float)(start + cs);
        out[2 * NK + o] = vx;
    }
    for (int k2 = lane; k2 < K; k2 += 64)          // centers chunk
        out[NK + r * K + k2] = (float)r;
    const int m = __popcll(__ballot(v[0] < CUTOFF_F));
    if (m < K) do_fill<1>(v, m, K, lane, start, end, n, r, NK, out);
}

__device__ __forceinline__ void row_core_sort128(const float* __restrict__ pos,
                                                 int n, int lane,
                                                 int start, int end, int r,
                                                 float* __restrict__ out,
                                                 int NK, int K) {
    const int cA = lane, cB = 64 + lane;
    const int d  = r - start;                      // uniform, in [0, n)
    const int gA = start + min(cA, n - 1);
    const int gB = start + min(cB, n - 1);
    const float xa = pos[gA * 3 + 0], ya = pos[gA * 3 + 1], za = pos[gA * 3 + 2];
    const float xb = pos[gB * 3 + 0], yb = pos[gB * 3 + 1], zb = pos[gB * 3 + 2];
    const float sqa = __fadd_rn(__fadd_rn(__fmul_rn(xa, xa), __fmul_rn(ya, ya)),
                                __fmul_rn(za, za));
    const float sqb = __fadd_rn(__fadd_rn(__fmul_rn(xb, xb), __fmul_rn(yb, yb)),
                                __fmul_rn(zb, zb));
    float4 pr;
    if (d < 64) pr = make_float4(readlane_f(xa, d), readlane_f(ya, d),
                                 readlane_f(za, d), readlane_f(sqa, d));
    else        pr = make_float4(readlane_f(xb, d - 64), readlane_f(yb, d - 64),
                                 readlane_f(zb, d - 64), readlane_f(sqb, d - 64));
    float v[2];
    v[0] = (cA < n && cA != d) ? dist_v(pr, make_float4(xa, ya, za, sqa), false)
                               : CUTOFF_F;
    v[1] = (cB < n && cB != d) ? dist_v(pr, make_float4(xb, yb, zb, sqb), false)
                               : CUTOFF_F;

    unsigned ka = (((unsigned)__float_as_int(v[0])) & KEY_TRUNC) | (unsigned)cA;
    unsigned kb = (((unsigned)__float_as_int(v[1])) & KEY_TRUNC) | (unsigned)cB;
    bitonic128_u32(ka, kb, lane);

    const int   csa = (int)(ka & 0x7Fu);
    const float g0  = bperm_f(v[0], csa & 63);
    const float g1  = bperm_f(v[1], csa & 63);
    const float vxa = (csa < 64) ? g0 : g1;        // exact weight
    if (lane < K && vxa < CUTOFF_F) {
        const int o = r * K + lane;
        out[o]          = (float)(start + csa);
        out[2 * NK + o] = vxa;
    }
    if (64 + lane < K) {                           // K<=64: cold, kept for generality
        const int   csb = (int)(kb & 0x7Fu);
        const float h0  = bperm_f(v[0], csb & 63);
        const float h1  = bperm_f(v[1], csb & 63);
        const float vxb = (csb < 64) ? h0 : h1;
        if (vxb < CUTOFF_F) {
            const int o = r * K + 64 + lane;
            out[o]          = (float)(start + csb);
            out[2 * NK + o] = vxb;
        }
    }
    for (int k2 = lane; k2 < K; k2 += 64)
        out[NK + r * K + k2] = (float)r;
    const int m = __popcll(__ballot(v[0] < CUTOFF_F))
                + __popcll(__ballot(v[1] < CUTOFF_F));
    if (m < K) do_fill<2>(v, m, K, lane, start, end, n, r, NK, out);
}

// ------------- cold paths: own register allocation (noinline) -----------------
__device__ __attribute__((noinline))
int lower_bound_cold(const int* __restrict__ batch, int lo, int hi, int key) {
    while (lo < hi) {
        int mid = (lo + hi) >> 1;
        if (batch[mid] < key) lo = mid + 1; else hi = mid;
    }
    return lo;
}

__device__ __attribute__((noinline))
void row_core_fallback(const float* __restrict__ pos, float4 pr, int n, int lane,
                       int start, int end, int r, float* __restrict__ out,
                       int NK, int K) {
    // exact rank-based path for n > 128 (never taken with bench inputs)
    int m = 0;
    for (int cb = 0; cb < n; cb += 64) {
        const int c = cb + lane;
        const float v = (c < n)
            ? dist_v(pr, load_pos4(pos, start + c), (start + c) == r) : CUTOFF_F;
        int rk = 0;
        for (int cc = 0; cc < n; ++cc) {
            const float vv = dist_v(pr, load_pos4(pos, start + cc), (start + cc) == r);
            rk += (vv < v) || (vv == v && cc < c);
        }
        if (c < n && v < CUTOFF_F && rk < K) {
            const int o = r * K + rk;
            out[o]          = (float)(start + c);
            out[2 * NK + o] = v;
        }
        m += __popcll(__ballot(c < n && v < CUTOFF_F));
    }
    for (int k2 = lane; k2 < K; k2 += 64)
        out[NK + r * K + k2] = (float)r;
    if (m < K) {
        const int mm = n - m;
        for (int fb = 0; fb < K - m; fb += 64) {
            const int t = fb + lane;
            const bool active = t < (K - m);
            int idx = 0; bool found = false;
            if (active) {
                if (t < start)            { idx = t;                      found = true; }
                else if (t - start >= mm) { idx = end + (t - start - mm); found = true; }
            }
            if (__any(active && !found)) {
                int cnt = 0;
                for (int cc = 0; cc < n; ++cc) {
                    if (dist_v(pr, load_pos4(pos, start + cc), (start + cc) == r)
                        == CUTOFF_F) {
                        if (active && !found && cnt == t - start) {
                            idx = start + cc; found = true;
                        }
                        ++cnt;
                    }
                }
            }
            if (active) {
                const int o = r * K + m + t;
                out[o]          = (float)idx;
                out[2 * NK + o] = CUTOFF_F;
            }
        }
    }
}

// ---------------- per-row engine (R12 body, bitwise-identical outputs) --------
__device__ __attribute__((noinline))
void process_row(const float* __restrict__ pos, const int* __restrict__ batch,
                 float* __restrict__ out, int N, int K, int r, int lane) {
    const int NK = N * K;

    const int iu = r - 63 + lane;             // upward window: idx r-63 .. r
    const int id = r + 1 + lane;              // downward window: idx r+1 .. r+64
    const int au = batch[max(iu, 0)];
    const int ad = batch[min(id, N - 1)];

    const int b = readlane_i(au, 63);         // batch[r]

    const unsigned long long mu = __ballot(iu >= 0 && au == b);
    int start;
    if (mu != ~0ull) {
        start = r - __builtin_clzll(~mu) + 1;
    } else {
        const int iu2 = r - 127 + lane;
        const unsigned long long mu2 =
            __ballot(iu2 >= 0 && batch[max(iu2, 0)] == b);
        if (mu2 != ~0ull)           start = r - 63 - __builtin_clzll(~mu2);
        else if (r - 127 <= 0)      start = 0;
        else                        start = lower_bound_cold(batch, 0, r, b);
    }

    const unsigned long long md = __ballot(id < N && ad == b);
    int end;
    if (md != ~0ull) {
        end = r + 1 + __builtin_ctzll(~md);
    } else {
        const int id2 = r + 65 + lane;
        const unsigned long long md2 =
            __ballot(id2 < N && batch[min(id2, N - 1)] == b);
        if (md2 != ~0ull)           end = r + 65 + __builtin_ctzll(~md2);
        else if (r + 129 >= N)      end = N;
        else                        end = lower_bound_cold(batch, r + 1, N, b + 1);
    }

    const int n = end - start;

    if      (n <= 64)  row_core_sort64 (pos, n, lane, start, end, r, out, NK, K);
    else if (n <= 128) row_core_sort128(pos, n, lane, start, end, r, out, NK, K);
    else               row_core_fallback(pos, load_pos4(pos, r), n, lane, start,
                                         end, r, out, NK, K);
}

// ---------------- kernel ------------------------------------------------------
__global__ __launch_bounds__(256, 8)
void knn_fused_kernel(const float* __restrict__ pos,
                      const int* __restrict__ batch,
                      float* __restrict__ out,
                      int N, int K) {
    const int w    = threadIdx.x >> 6;
    const int lane = threadIdx.x & 63;
    const int r0   = (blockIdx.x * WAVES_PER_BLOCK + w) * ROWS_PER_WAVE;
#pragma unroll
    for (int i = 0; i < ROWS_PER_WAVE; ++i) {
        const int r = r0 + i;
        if (r < N) process_row(pos, batch, out, N, K, r, lane);
    }
}

extern "C" void kernel_launch(void* const* d_in, const int* in_sizes, int n_in,
                              void* d_out, int out_size, void* d_ws, size_t ws_size,
                              hipStream_t stream) {
    const float* pos   = (const float*)d_in[0];   // [N,3] float32
    const int*   batch = (const int*)d_in[1];     // [N]   int32, sorted
    float*       out   = (float*)d_out;           // float32, 3*N*K

    const int N = in_sizes[1];            // 8192
    const int K = out_size / (3 * N);     // 32

    const int grid = (N + ROWS_PER_BLOCK - 1) / ROWS_PER_BLOCK;  // 1024
    knn_fused_kernel<<<grid, 256, 0, stream>>>(pos, batch, out, N, K);
}

// Round 14
// 59.124 us; speedup vs baseline: 1.0300x; 1.0300x over previous
//
#include <hip/hip_runtime.h>

// KNNInteractionGraph — row-per-wave bitonic selection (R12 config, best
// measured: 59.90us) + dead-stage cut in the 128-merge tail.
// N=8192, K=32, CUTOFF=10, batch sorted (molecules contiguous, n ~ 64+-8).
//
// Ledger (R5-R13): kernel ~10us warm, latency-bound on the per-wave dependent
// chain; WG count / wave count (both directions) / spills / per-wave dispatch
// all measured neutral; only cross-lane+VALU cuts paid (R8/R11/R12).
// R14 cut: in bitonic128's final k=128 merge, after the in-lane exchange the
// j<64 stages on kb only affect output slots >=64, which are never read when
// K<=64 -> skip them (uniform guard). ka (slots 0..63) bit-identical.
//
// Output (float32, 3*N*K): [indices | centers | weights].

#define CUTOFF_F 10.0f
#define ROWS_PER_BLOCK 4
#define KEY_TRUNC 0xFFFFFF80u     // keep 25 high bits of v, low 7 bits = col

__device__ __forceinline__ float readlane_f(float v, int lane) {
    return __int_as_float(__builtin_amdgcn_readlane(__float_as_int(v), lane));
}
__device__ __forceinline__ int readlane_i(int v, int lane) {
    return __builtin_amdgcn_readlane(v, lane);
}
__device__ __forceinline__ float bperm_f(float v, int srclane) {
    return __int_as_float(__builtin_amdgcn_ds_bpermute(srclane << 2, __float_as_int(v)));
}

// DPP xor-permutations: quad_perm xor1 = 0xB1, quad_perm xor2 = 0x4E,
// row_ror:8 = 0x128 (== xor8 within 16-lane rows). All lanes active (EXEC=~0).
template <int CTRL>
__device__ __forceinline__ unsigned dpp_u32(unsigned x) {
    return (unsigned)__builtin_amdgcn_update_dpp((int)x, (int)x, CTRL, 0xf, 0xf, true);
}
__device__ __forceinline__ unsigned stage_shfl32(unsigned x, int j) {
    if (j == 1) return dpp_u32<0xB1>(x);
    if (j == 2) return dpp_u32<0x4E>(x);
    if (j == 8) return dpp_u32<0x128>(x);
    return (unsigned)__shfl_xor((int)x, j, 64);
}

// Reference-exact masked distance (gram expansion, f32, no FMA contraction):
__device__ __forceinline__ float dist_v(float4 pr, float4 pc, bool diag) {
    if (diag) return CUTOFF_F;
    float dot = __fadd_rn(__fadd_rn(__fmul_rn(pr.x, pc.x), __fmul_rn(pr.y, pc.y)),
                          __fmul_rn(pr.z, pc.z));
    float sq = __fsub_rn(__fadd_rn(pr.w, pc.w), __fadd_rn(dot, dot));
    sq = fmaxf(sq, 0.0f);
    float d = (sq > 0.0f) ? __fsqrt_rn(sq) : 0.0f;
    return (d > CUTOFF_F) ? CUTOFF_F : d;
}

__device__ __forceinline__ float4 load_pos4(const float* __restrict__ pos, int g) {
    float x = pos[g * 3 + 0];
    float y = pos[g * 3 + 1];
    float z = pos[g * 3 + 2];
    float sq = __fadd_rn(__fadd_rn(__fmul_rn(x, x), __fmul_rn(y, y)), __fmul_rn(z, z));
    return make_float4(x, y, z, sq);
}

// Ascending bitonic sort of 64 u32 keys, one per lane.
__device__ __forceinline__ unsigned bitonic64_u32(unsigned key, int lane) {
#pragma unroll
    for (int k = 2; k <= 64; k <<= 1) {
#pragma unroll
        for (int j = k >> 1; j > 0; j >>= 1) {
            const unsigned pk = stage_shfl32(key, j);
            const bool take_min = (((lane & j) == 0) == ((lane & k) == 0));
            key = ((pk < key) == take_min) ? pk : key;
        }
    }
    return key;
}

// Ascending bitonic sort of 128 u32 keys, two per lane (A: vpos=lane,
// B: vpos=64+lane). If need_b is false (K<=64), the final-merge tail stages on
// kb are skipped: after the k=128 j=64 in-lane exchange, lower/upper halves are
// independent for j<64, and slots >=64 (kb) are never read.
__device__ __forceinline__ void bitonic128_u32(unsigned& ka, unsigned& kb, int lane,
                                               bool need_b) {
#pragma unroll
    for (int k = 2; k <= 128; k <<= 1) {
#pragma unroll
        for (int j = k >> 1; j > 0; j >>= 1) {
            if (j == 64) {            // final k=128 merge: in-lane A<->B
                const unsigned mn = min(ka, kb);
                const unsigned mx = max(ka, kb);
                ka = mn; kb = mx;
            } else {
                const bool low = ((lane & j) == 0);
                const bool upA = ((lane & k) == 0);
                const bool upB = (k == 64) ? false : upA;
                const unsigned pa = stage_shfl32(ka, j);
                ka = ((pa < ka) == (low == upA)) ? pa : ka;
                if (k < 128 || need_b) {          // kb tail dead for K<=64
                    const unsigned pb = stage_shfl32(kb, j);
                    kb = ((pb < kb) == (low == upB)) ? pb : kb;
                }
            }
        }
    }
}

// Cold fill: slots [m,K) get CUTOFF at globally-smallest masked indices:
// {0..start-1} U {in-mol masked (v==CUTOFF)} U {end..N-1} (lax.top_k tie order).
template <int NCH>
__device__ __forceinline__ void do_fill(const float* v, int m, int K, int lane,
                                        int start, int end, int n, int r, int NK,
                                        float* __restrict__ out) {
    const int mm = n - m;
    for (int fb = 0; fb < K - m; fb += 64) {
        const int t = fb + lane;
        const bool active = t < (K - m);
        int idx = 0;
        bool found = false;
        if (active) {
            if (t < start)            { idx = t;                      found = true; }
            else if (t - start >= mm) { idx = end + (t - start - mm); found = true; }
        }
        if (__any(active && !found)) {
            int cnt = 0;
#pragma unroll
            for (int jj = 0; jj < NCH; ++jj) {
                const int base = 64 * jj;
                const int lim  = min(n - base, 64);
                for (int cc = 0; cc < lim; ++cc) {
                    if (readlane_f(v[jj], cc) == CUTOFF_F) {
                        if (active && !found && cnt == t - start) {
                            idx = start + base + cc; found = true;
                        }
                        ++cnt;
                    }
                }
            }
        }
        if (active) {
            const int o = r * K + m + t;
            out[o]          = (float)idx;
            out[2 * NK + o] = CUTOFF_F;
        }
    }
}

// ---------------- hot cores ---------------------------------------------------
__device__ __forceinline__ void row_core_sort64(const float* __restrict__ pos,
                                                int n, int lane,
                                                int start, int end, int r,
                                                float* __restrict__ out,
                                                int NK, int K) {
    const int c = lane;
    const int d = r - start;                       // uniform, in [0, n)
    const int g = start + min(c, n - 1);           // clamped column load
    const float x = pos[g * 3 + 0];
    const float y = pos[g * 3 + 1];
    const float z = pos[g * 3 + 2];
    const float sq = __fadd_rn(__fadd_rn(__fmul_rn(x, x), __fmul_rn(y, y)),
                               __fmul_rn(z, z));
    const float4 pc = make_float4(x, y, z, sq);
    const float4 pr = make_float4(readlane_f(x, d), readlane_f(y, d),
                                  readlane_f(z, d), readlane_f(sq, d));
    float v[1];
    v[0] = (c < n && c != d) ? dist_v(pr, pc, false) : CUTOFF_F;

    unsigned key = (((unsigned)__float_as_int(v[0])) & KEY_TRUNC) | (unsigned)c;
    key = bitonic64_u32(key, lane);

    const int   cs = (int)(key & 0x7Fu);
    const float vx = bperm_f(v[0], cs);            // exact weight by sorted col
    if (lane < K && vx < CUTOFF_F) {               // sorted slot = lane (coalesced)
        const int o = r * K + lane;
        out[o]          = (float)(start + cs);
        out[2 * NK + o] = vx;
    }
    for (int k2 = lane; k2 < K; k2 += 64)          // centers chunk
        out[NK + r * K + k2] = (float)r;
    const int m = __popcll(__ballot(v[0] < CUTOFF_F));
    if (m < K) do_fill<1>(v, m, K, lane, start, end, n, r, NK, out);
}

__device__ __forceinline__ void row_core_sort128(const float* __restrict__ pos,
                                                 int n, int lane,
                                                 int start, int end, int r,
                                                 float* __restrict__ out,
                                                 int NK, int K) {
    const int cA = lane, cB = 64 + lane;
    const int d  = r - start;                      // uniform, in [0, n)
    const int gA = start + min(cA, n - 1);
    const int gB = start + min(cB, n - 1);
    const float xa = pos[gA * 3 + 0], ya = pos[gA * 3 + 1], za = pos[gA * 3 + 2];
    const float xb = pos[gB * 3 + 0], yb = pos[gB * 3 + 1], zb = pos[gB * 3 + 2];
    const float sqa = __fadd_rn(__fadd_rn(__fmul_rn(xa, xa), __fmul_rn(ya, ya)),
                                __fmul_rn(za, za));
    const float sqb = __fadd_rn(__fadd_rn(__fmul_rn(xb, xb), __fmul_rn(yb, yb)),
                                __fmul_rn(zb, zb));
    float4 pr;
    if (d < 64) pr = make_float4(readlane_f(xa, d), readlane_f(ya, d),
                                 readlane_f(za, d), readlane_f(sqa, d));
    else        pr = make_float4(readlane_f(xb, d - 64), readlane_f(yb, d - 64),
                                 readlane_f(zb, d - 64), readlane_f(sqb, d - 64));
    float v[2];
    v[0] = (cA < n && cA != d) ? dist_v(pr, make_float4(xa, ya, za, sqa), false)
                               : CUTOFF_F;
    v[1] = (cB < n && cB != d) ? dist_v(pr, make_float4(xb, yb, zb, sqb), false)
                               : CUTOFF_F;

    unsigned ka = (((unsigned)__float_as_int(v[0])) & KEY_TRUNC) | (unsigned)cA;
    unsigned kb = (((unsigned)__float_as_int(v[1])) & KEY_TRUNC) | (unsigned)cB;
    bitonic128_u32(ka, kb, lane, /*need_b=*/(K > 64));

    const int   csa = (int)(ka & 0x7Fu);
    const float g0  = bperm_f(v[0], csa & 63);
    const float g1  = bperm_f(v[1], csa & 63);
    const float vxa = (csa < 64) ? g0 : g1;        // exact weight
    if (lane < K && vxa < CUTOFF_F) {
        const int o = r * K + lane;
        out[o]          = (float)(start + csa);
        out[2 * NK + o] = vxa;
    }
    if (64 + lane < K) {                           // only reachable when K>64
        const int   csb = (int)(kb & 0x7Fu);
        const float h0  = bperm_f(v[0], csb & 63);
        const float h1  = bperm_f(v[1], csb & 63);
        const float vxb = (csb < 64) ? h0 : h1;
        if (vxb < CUTOFF_F) {
            const int o = r * K + 64 + lane;
            out[o]          = (float)(start + csb);
            out[2 * NK + o] = vxb;
        }
    }
    for (int k2 = lane; k2 < K; k2 += 64)
        out[NK + r * K + k2] = (float)r;
    const int m = __popcll(__ballot(v[0] < CUTOFF_F))
                + __popcll(__ballot(v[1] < CUTOFF_F));
    if (m < K) do_fill<2>(v, m, K, lane, start, end, n, r, NK, out);
}

// ------------- cold paths: own register allocation (noinline) -----------------
__device__ __attribute__((noinline))
int lower_bound_cold(const int* __restrict__ batch, int lo, int hi, int key) {
    while (lo < hi) {
        int mid = (lo + hi) >> 1;
        if (batch[mid] < key) lo = mid + 1; else hi = mid;
    }
    return lo;
}

__device__ __attribute__((noinline))
void row_core_fallback(const float* __restrict__ pos, float4 pr, int n, int lane,
                       int start, int end, int r, float* __restrict__ out,
                       int NK, int K) {
    // exact rank-based path for n > 128 (never taken with bench inputs)
    int m = 0;
    for (int cb = 0; cb < n; cb += 64) {
        const int c = cb + lane;
        const float v = (c < n)
            ? dist_v(pr, load_pos4(pos, start + c), (start + c) == r) : CUTOFF_F;
        int rk = 0;
        for (int cc = 0; cc < n; ++cc) {
            const float vv = dist_v(pr, load_pos4(pos, start + cc), (start + cc) == r);
            rk += (vv < v) || (vv == v && cc < c);
        }
        if (c < n && v < CUTOFF_F && rk < K) {
            const int o = r * K + rk;
            out[o]          = (float)(start + c);
            out[2 * NK + o] = v;
        }
        m += __popcll(__ballot(c < n && v < CUTOFF_F));
    }
    for (int k2 = lane; k2 < K; k2 += 64)
        out[NK + r * K + k2] = (float)r;
    if (m < K) {
        const int mm = n - m;
        for (int fb = 0; fb < K - m; fb += 64) {
            const int t = fb + lane;
            const bool active = t < (K - m);
            int idx = 0; bool found = false;
            if (active) {
                if (t < start)            { idx = t;                      found = true; }
                else if (t - start >= mm) { idx = end + (t - start - mm); found = true; }
            }
            if (__any(active && !found)) {
                int cnt = 0;
                for (int cc = 0; cc < n; ++cc) {
                    if (dist_v(pr, load_pos4(pos, start + cc), (start + cc) == r)
                        == CUTOFF_F) {
                        if (active && !found && cnt == t - start) {
                            idx = start + cc; found = true;
                        }
                        ++cnt;
                    }
                }
            }
            if (active) {
                const int o = r * K + m + t;
                out[o]          = (float)idx;
                out[2 * NK + o] = CUTOFF_F;
            }
        }
    }
}

// ---------------- kernel ------------------------------------------------------
__global__ __launch_bounds__(256, 8)
void knn_fused_kernel(const float* __restrict__ pos,
                      const int* __restrict__ batch,
                      float* __restrict__ out,
                      int N, int K) {
    const int w    = threadIdx.x >> 6;
    const int lane = threadIdx.x & 63;
    const int r    = blockIdx.x * ROWS_PER_BLOCK + w;
    if (r >= N) return;                       // no shared vars, no barriers
    const int NK = N * K;

    const int iu = r - 63 + lane;             // upward window: idx r-63 .. r
    const int id = r + 1 + lane;              // downward window: idx r+1 .. r+64
    const int au = batch[max(iu, 0)];
    const int ad = batch[min(id, N - 1)];

    const int b = readlane_i(au, 63);         // batch[r]

    const unsigned long long mu = __ballot(iu >= 0 && au == b);
    int start;
    if (mu != ~0ull) {
        start = r - __builtin_clzll(~mu) + 1;
    } else {
        const int iu2 = r - 127 + lane;
        const unsigned long long mu2 =
            __ballot(iu2 >= 0 && batch[max(iu2, 0)] == b);
        if (mu2 != ~0ull)           start = r - 63 - __builtin_clzll(~mu2);
        else if (r - 127 <= 0)      start = 0;
        else                        start = lower_bound_cold(batch, 0, r, b);
    }

    const unsigned long long md = __ballot(id < N && ad == b);
    int end;
    if (md != ~0ull) {
        end = r + 1 + __builtin_ctzll(~md);
    } else {
        const int id2 = r + 65 + lane;
        const unsigned long long md2 =
            __ballot(id2 < N && batch[min(id2, N - 1)] == b);
        if (md2 != ~0ull)           end = r + 65 + __builtin_ctzll(~md2);
        else if (r + 129 >= N)      end = N;
        else                        end = lower_bound_cold(batch, r + 1, N, b + 1);
    }

    const int n = end - start;

    if      (n <= 64)  row_core_sort64 (pos, n, lane, start, end, r, out, NK, K);
    else if (n <= 128) row_core_sort128(pos, n, lane, start, end, r, out, NK, K);
    else               row_core_fallback(pos, load_pos4(pos, r), n, lane, start,
                                         end, r, out, NK, K);
}

extern "C" void kernel_launch(void* const* d_in, const int* in_sizes, int n_in,
                              void* d_out, int out_size, void* d_ws, size_t ws_size,
                              hipStream_t stream) {
    const float* pos   = (const float*)d_in[0];   // [N,3] float32
    const int*   batch = (const int*)d_in[1];     // [N]   int32, sorted
    float*       out   = (float*)d_out;           // float32, 3*N*K

    const int N = in_sizes[1];            // 8192
    const int K = out_size / (3 * N);     // 32

    const int grid = (N + ROWS_PER_BLOCK - 1) / ROWS_PER_BLOCK;  // 2048
    knn_fused_kernel<<<grid, 256, 0, stream>>>(pos, batch, out, N, K);
}